// Round 3
// baseline (672.440 us; speedup 1.0000x reference)
//
#include <hip/hip_runtime.h>
#include <hip/hip_bf16.h>

typedef __attribute__((ext_vector_type(4))) float f32x4;
typedef __attribute__((ext_vector_type(4))) float fl4;
typedef __attribute__((ext_vector_type(8))) short s16x8;
typedef __attribute__((ext_vector_type(4))) short s16x4;

#define SCALING_C 0.1889822365046136f
#define SOFTCAP_C 50.0f

__device__ __forceinline__ short f2bf(float f) {
  union { float f; unsigned u; } v; v.f = f;
  unsigned r = v.u + 0x7fffu + ((v.u >> 16) & 1u);
  return (short)(r >> 16);
}

// ---------------- GEMM: C = A @ B, A row-major MxK, B row-major KxN ----------------
#define BM 128
#define BN 128
#define BKK 32
#define KPAD 40   // 40 shorts = 80B row stride: 16B-aligned for ds b128 frag reads

template<int A_BF16, int OUT_BF16>
__global__ __launch_bounds__(256)
void gemm_kernel(const void* __restrict__ Av, const float* __restrict__ B,
                 void* __restrict__ Cv, int M, int N, int K) {
  __shared__ short As[BM][KPAD];
  __shared__ short Bs[BN][KPAD];   // B stored transposed: Bs[n][k]
  const int tid = threadIdx.x;
  const int bm = blockIdx.y, bn = blockIdx.x;
  const int wid = tid >> 6, lane = tid & 63;
  const int wr = (wid >> 1) * 64, wc = (wid & 1) * 64;
  const int ar = lane & 15, ko = (lane >> 4) * 8;
  const f32x4 fz = {0.f, 0.f, 0.f, 0.f};
  f32x4 acc[4][4];
#pragma unroll
  for (int m = 0; m < 4; ++m)
#pragma unroll
    for (int n = 0; n < 4; ++n) acc[m][n] = fz;

  for (int k0 = 0; k0 < K; k0 += BKK) {
    // stage A tile (BM x BKK): 1024 tasks of 4 elements
#pragma unroll
    for (int i = 0; i < 4; ++i) {
      int idx = tid + i * 256;
      int row = idx >> 3;
      int kc = (idx & 7) * 4;
      if (A_BF16) {
        *(s16x4*)&As[row][kc] =
            *(const s16x4*)((const short*)Av + (size_t)(bm * BM + row) * K + k0 + kc);
      } else {
        fl4 v = *(const fl4*)((const float*)Av + (size_t)(bm * BM + row) * K + k0 + kc);
        s16x4 o;
        o[0] = f2bf(v[0]); o[1] = f2bf(v[1]); o[2] = f2bf(v[2]); o[3] = f2bf(v[3]);
        *(s16x4*)&As[row][kc] = o;
      }
    }
    // stage B tile (BKK x BN) transposed into Bs[n][k]; thread gathers 4 k for one n
#pragma unroll
    for (int i = 0; i < 4; ++i) {
      int idx = tid + i * 256;
      int n = idx & 127;
      int kr4 = (idx >> 7) * 4;
      s16x4 o;
#pragma unroll
      for (int j = 0; j < 4; ++j)
        o[j] = f2bf(B[(size_t)(k0 + kr4 + j) * N + bn * BN + n]);
      *(s16x4*)&Bs[n][kr4] = o;
    }
    __syncthreads();
    s16x8 af[4], bfr[4];
#pragma unroll
    for (int m = 0; m < 4; ++m) af[m] = *(const s16x8*)&As[wr + m * 16 + ar][ko];
#pragma unroll
    for (int n = 0; n < 4; ++n) bfr[n] = *(const s16x8*)&Bs[wc + n * 16 + ar][ko];
#pragma unroll
    for (int m = 0; m < 4; ++m)
#pragma unroll
      for (int n = 0; n < 4; ++n)
        acc[m][n] = __builtin_amdgcn_mfma_f32_16x16x32_bf16(af[m], bfr[n], acc[m][n], 0, 0, 0);
    __syncthreads();
  }
  // epilogue: C/D layout col = lane&15, row = (lane>>4)*4 + j
#pragma unroll
  for (int m = 0; m < 4; ++m)
#pragma unroll
    for (int n = 0; n < 4; ++n)
#pragma unroll
      for (int j = 0; j < 4; ++j) {
        int row = bm * BM + wr + m * 16 + (lane >> 4) * 4 + j;
        int col = bn * BN + wc + n * 16 + ar;
        if (OUT_BF16)
          ((short*)Cv)[(size_t)row * N + col] = f2bf(acc[m][n][j]);
        else
          ((float*)Cv)[(size_t)row * N + col] = acc[m][n][j];
      }
}

// ---------------- fused RMSNorm + RoPE, one wave per (s,h) row of 128 ----------------
__global__ __launch_bounds__(256)
void normrope_kernel(const float* __restrict__ X, const float* __restrict__ cosb,
                     const float* __restrict__ sinb, const float* __restrict__ w,
                     short* __restrict__ out, int nhshift) {
  const int wid = threadIdx.x >> 6, lane = threadIdx.x & 63;
  const int r = blockIdx.x * 4 + wid;
  const int s = r >> nhshift;
  const size_t base = (size_t)r * 128;
  float x1 = X[base + lane];
  float x2 = X[base + 64 + lane];
  float ss = x1 * x1 + x2 * x2;
#pragma unroll
  for (int m = 1; m < 64; m <<= 1) ss += __shfl_xor(ss, m);
  float inv = rsqrtf(ss * (1.0f / 128.0f) + 1e-6f);
  float n1 = x1 * inv * (1.0f + w[lane]);
  float n2 = x2 * inv * (1.0f + w[lane + 64]);
  float c1 = cosb[s * 128 + lane], sn1 = sinb[s * 128 + lane];
  float c2 = cosb[s * 128 + 64 + lane], sn2 = sinb[s * 128 + 64 + lane];
  out[base + lane] = f2bf(n1 * c1 - n2 * sn1);
  out[base + 64 + lane] = f2bf(n2 * c2 + n1 * sn2);
}

// ---------------- flash attention, causal, GQA 4:1, softcap ----------------
// grid: (qb=32, h=32), 256 threads (4 waves); wave w owns q rows qb*64 + w*16 .. +15
__global__ __launch_bounds__(256)
void attn_kernel(const short* __restrict__ Q, const short* __restrict__ K,
                 const short* __restrict__ V, short* __restrict__ O) {
  __shared__ short Ks[64][136];      // [kk][d], stride 272B (16B aligned, non-pow2 banks)
  __shared__ short Vt[128][72];      // [d][kk] transposed, stride 144B
  __shared__ short Ps[4][16][72];    // per-wave P tile [q][kk]
  const int tid = threadIdx.x;
  const int qb = blockIdx.x, h = blockIdx.y;
  const int hk = h >> 2;
  const int wid = tid >> 6, lane = tid & 63;
  const int ar = lane & 15, g = lane >> 4, ko = g * 8;
  const int rbase = g * 4;
  const int q0 = qb * 64 + wid * 16;

  // Q fragments live in registers for the whole kernel
  s16x8 qf[4];
#pragma unroll
  for (int ks = 0; ks < 4; ++ks)
    qf[ks] = *(const s16x8*)&Q[(size_t)(q0 + ar) * 4096 + h * 128 + ks * 32 + ko];

  const f32x4 fz = {0.f, 0.f, 0.f, 0.f};
  float m_i[4], l_i[4];
  f32x4 oacc[8];
#pragma unroll
  for (int j = 0; j < 4; ++j) { m_i[j] = -INFINITY; l_i[j] = 0.f; }
#pragma unroll
  for (int n = 0; n < 8; ++n) oacc[n] = fz;

  for (int kb = 0; kb <= qb; ++kb) {
    // stage K tile 64x128 (linear copy, b128 in/out)
#pragma unroll
    for (int i = 0; i < 4; ++i) {
      int idx = tid + i * 256;
      int row = idx >> 4, c8 = (idx & 15) * 8;
      *(s16x8*)&Ks[row][c8] =
          *(const s16x8*)&K[(size_t)(kb * 64 + row) * 1024 + hk * 128 + c8];
    }
    // stage V transposed: thread gathers 4 kk (coalesced per j across lanes) for one d
#pragma unroll
    for (int i = 0; i < 8; ++i) {
      int idx = tid + i * 256;
      int d = idx & 127, kk4 = (idx >> 7) * 4;
      const short* vp = &V[(size_t)(kb * 64 + kk4) * 1024 + hk * 128 + d];
      s16x4 tv;
      tv[0] = vp[0]; tv[1] = vp[1024]; tv[2] = vp[2048]; tv[3] = vp[3072];
      *(s16x4*)&Vt[d][kk4] = tv;
    }
    __syncthreads();

    // S = Q K^T  (per wave: 16q x 64kk)
    f32x4 sacc[4];
#pragma unroll
    for (int n = 0; n < 4; ++n) sacc[n] = fz;
#pragma unroll
    for (int ks = 0; ks < 4; ++ks)
#pragma unroll
      for (int n = 0; n < 4; ++n) {
        s16x8 bfr = *(const s16x8*)&Ks[n * 16 + ar][ks * 32 + ko];
        sacc[n] = __builtin_amdgcn_mfma_f32_16x16x32_bf16(qf[ks], bfr, sacc[n], 0, 0, 0);
      }

    // softcap + causal mask + row max
    float rmax[4];
#pragma unroll
    for (int j = 0; j < 4; ++j) rmax[j] = -INFINITY;
#pragma unroll
    for (int n = 0; n < 4; ++n)
#pragma unroll
      for (int j = 0; j < 4; ++j) {
        float s = sacc[n][j] * SCALING_C;
        s = SOFTCAP_C * tanhf(s * (1.0f / SOFTCAP_C));
        int kkg = kb * 64 + n * 16 + ar;
        int qg = q0 + rbase + j;
        if (kkg > qg) s = -1e9f;
        sacc[n][j] = s;
        rmax[j] = fmaxf(rmax[j], s);
      }
#pragma unroll
    for (int j = 0; j < 4; ++j) {
#pragma unroll
      for (int mm = 1; mm < 16; mm <<= 1)
        rmax[j] = fmaxf(rmax[j], __shfl_xor(rmax[j], mm));
    }
    // online softmax update; write P (bf16) to per-wave LDS tile
#pragma unroll
    for (int j = 0; j < 4; ++j) {
      float mn = fmaxf(m_i[j], rmax[j]);
      float alpha = __expf(m_i[j] - mn);
      float rs = 0.f;
#pragma unroll
      for (int n = 0; n < 4; ++n) {
        float p = __expf(sacc[n][j] - mn);
        rs += p;
        Ps[wid][rbase + j][n * 16 + ar] = f2bf(p);
      }
#pragma unroll
      for (int mm = 1; mm < 16; mm <<= 1) rs += __shfl_xor(rs, mm);
      l_i[j] = l_i[j] * alpha + rs;
      m_i[j] = mn;
#pragma unroll
      for (int n = 0; n < 8; ++n) oacc[n][j] *= alpha;
    }

    // O += P V   (per wave: 16q x 128d)
#pragma unroll
    for (int ks = 0; ks < 2; ++ks) {
      s16x8 pa = *(const s16x8*)&Ps[wid][ar][ks * 32 + ko];
#pragma unroll
      for (int n = 0; n < 8; ++n) {
        s16x8 bfr = *(const s16x8*)&Vt[n * 16 + ar][ks * 32 + ko];
        oacc[n] = __builtin_amdgcn_mfma_f32_16x16x32_bf16(pa, bfr, oacc[n], 0, 0, 0);
      }
    }
    __syncthreads();
  }

  // epilogue: divide by l, write bf16 [q][h][d]
#pragma unroll
  for (int n = 0; n < 8; ++n)
#pragma unroll
    for (int j = 0; j < 4; ++j) {
      int q = q0 + rbase + j;
      int d = n * 16 + ar;
      O[(size_t)q * 4096 + h * 128 + d] = f2bf(oacc[n][j] / l_i[j]);
    }
}

extern "C" void kernel_launch(void* const* d_in, const int* in_sizes, int n_in,
                              void* d_out, int out_size, void* d_ws, size_t ws_size,
                              hipStream_t stream) {
  const float* hs   = (const float*)d_in[0];
  const float* cosb = (const float*)d_in[1];
  const float* sinb = (const float*)d_in[2];
  // d_in[3] attention_mask: pure causal triu(MASK_VALUE), applied analytically
  const float* Wq = (const float*)d_in[4];
  const float* Wk = (const float*)d_in[5];
  const float* Wv = (const float*)d_in[6];
  const float* Wo = (const float*)d_in[7];
  const float* qw = (const float*)d_in[8];
  const float* kw = (const float*)d_in[9];
  float* out = (float*)d_out;

  char* ws = (char*)d_ws;
  float* Qf = (float*)ws;                    // 2048*4096*4 = 33.55 MB
  float* Kf = (float*)(ws + 33554432);       // 2048*1024*4 =  8.39 MB
  short* Qb = (short*)(ws + 41943040);       // 2048*4096*2 = 16.78 MB
  short* Kb = (short*)(ws + 58720256);       //               4.19 MB
  short* Vb = (short*)(ws + 62914560);       //               4.19 MB (end 67.1 MB)
  short* ao = (short*)ws;                    // aliases Qf (dead after rope-Q)

  dim3 blk(256);
  gemm_kernel<0, 0><<<dim3(32, 16), blk, 0, stream>>>(hs, Wq, Qf, 2048, 4096, 2560);
  gemm_kernel<0, 0><<<dim3(8, 16),  blk, 0, stream>>>(hs, Wk, Kf, 2048, 1024, 2560);
  gemm_kernel<0, 1><<<dim3(8, 16),  blk, 0, stream>>>(hs, Wv, Vb, 2048, 1024, 2560);
  normrope_kernel<<<16384, blk, 0, stream>>>(Qf, cosb, sinb, qw, Qb, 5);
  normrope_kernel<<<4096,  blk, 0, stream>>>(Kf, cosb, sinb, kw, Kb, 3);
  attn_kernel<<<dim3(32, 32), blk, 0, stream>>>(Qb, Kb, Vb, ao);
  gemm_kernel<1, 0><<<dim3(20, 16), blk, 0, stream>>>(ao, Wo, out, 2048, 2560, 4096);
}

// Round 4
// 608.678 us; speedup vs baseline: 1.1048x; 1.1048x over previous
//
#include <hip/hip_runtime.h>
#include <hip/hip_bf16.h>

typedef __attribute__((ext_vector_type(4))) float f32x4;
typedef __attribute__((ext_vector_type(4))) float fl4;
typedef __attribute__((ext_vector_type(8))) short s16x8;
typedef __attribute__((ext_vector_type(4))) short s16x4;

#define SCALING_C 0.1889822365046136f
#define SOFTCAP_C 50.0f
// tanh(s*SCALING/50) argument pre-scale: 2*SCALING/50
#define TANH_K 0.007559289460184544f

__device__ __forceinline__ short f2bf(float f) {
  union { float f; unsigned u; } v; v.f = f;
  unsigned r = v.u + 0x7fffu + ((v.u >> 16) & 1u);
  return (short)(r >> 16);
}
__device__ __forceinline__ float bf2f(short s) {
  union { unsigned u; float f; } v; v.u = ((unsigned)(unsigned short)s) << 16;
  return v.f;
}

#define GLOAD_LDS16(g, l)                                                          \
  __builtin_amdgcn_global_load_lds(                                                \
      (const __attribute__((address_space(1))) void*)(g),                          \
      (__attribute__((address_space(3))) void*)(l), 16, 0, 0)

// ---------------- transpose + fp32->bf16 convert: WT[n][k] = bf16(W[k][n]) -----
__global__ __launch_bounds__(256)
void convT_kernel(const float* __restrict__ W, short* __restrict__ WT, int K, int N) {
  __shared__ float T[64][65];
  const int tx = threadIdx.x, ty = threadIdx.y;   // (64,4)
  const int k0 = blockIdx.x * 64, n0 = blockIdx.y * 64;
#pragma unroll
  for (int i = 0; i < 16; ++i) {
    int r = ty + i * 4;
    T[r][tx] = W[(size_t)(k0 + r) * N + n0 + tx];
  }
  __syncthreads();
#pragma unroll
  for (int i = 0; i < 16; ++i) {
    int r = ty + i * 4;
    WT[(size_t)(n0 + r) * K + k0 + tx] = f2bf(T[tx][r]);
  }
}

// ---------------- fp32 -> bf16 elementwise (hidden states) ----------------
__global__ __launch_bounds__(256)
void conv16_kernel(const float* __restrict__ X, short* __restrict__ Y, int n4) {
  int i = blockIdx.x * 256 + threadIdx.x;
  if (i < n4) {
    fl4 v = *(const fl4*)&X[(size_t)i * 4];
    s16x4 o;
    o[0] = f2bf(v[0]); o[1] = f2bf(v[1]); o[2] = f2bf(v[2]); o[3] = f2bf(v[3]);
    *(s16x4*)&Y[(size_t)i * 4] = o;
  }
}

// ---------------- GEMM: C = A @ Bt^T ; A MxK bf16 rows, Bt NxK bf16 rows -------
// m97 structure: global_load_lds w16, BK=64, XOR source-swizzle (rule #21:
// linear LDS dest + inverse-swizzled global src + swizzled ds_read).
template<int OUT_BF16>
__global__ __launch_bounds__(256)
void gemm_bb(const short* __restrict__ A, const short* __restrict__ Bt,
             void* __restrict__ Cv, int N, int K) {
  __shared__ short As[8192];   // 128 rows x 64 shorts (8 x 16B units/row)
  __shared__ short Bs[8192];
  const int tid = threadIdx.x;
  const int bm = blockIdx.y, bn = blockIdx.x;
  const int wid = tid >> 6, lane = tid & 63;
  const int wr = (wid >> 1) * 64, wc = (wid & 1) * 64;
  const int ar = lane & 15, g = lane >> 4;

  const f32x4 fz = {0.f, 0.f, 0.f, 0.f};
  f32x4 acc[4][4];
#pragma unroll
  for (int m = 0; m < 4; ++m)
#pragma unroll
    for (int n = 0; n < 4; ++n) acc[m][n] = fz;

  const short* Abase = A + (size_t)(bm * 128) * K;
  const short* Bbase = Bt + (size_t)(bn * 128) * K;
  const int u0 = wid * 256 + lane;

  for (int k0 = 0; k0 < K; k0 += 64) {
#pragma unroll
    for (int i = 0; i < 4; ++i) {
      int u = u0 + i * 64;
      int r = u >> 3;
      int cs = (u & 7) ^ (r & 7);                 // inverse-swizzled source chunk
      size_t goff = (size_t)r * K + k0 + cs * 8;
      GLOAD_LDS16(Abase + goff, &As[(wid * 256 + i * 64) * 8]);
      GLOAD_LDS16(Bbase + goff, &Bs[(wid * 256 + i * 64) * 8]);
    }
    __syncthreads();
#pragma unroll
    for (int ks = 0; ks < 2; ++ks) {
      s16x8 af[4], bfr[4];
#pragma unroll
      for (int m = 0; m < 4; ++m) {
        int r = wr + m * 16 + ar;
        af[m] = *(const s16x8*)&As[r * 64 + (((ks * 4 + g) ^ (r & 7)) * 8)];
      }
#pragma unroll
      for (int n = 0; n < 4; ++n) {
        int r = wc + n * 16 + ar;
        bfr[n] = *(const s16x8*)&Bs[r * 64 + (((ks * 4 + g) ^ (r & 7)) * 8)];
      }
#pragma unroll
      for (int m = 0; m < 4; ++m)
#pragma unroll
        for (int n = 0; n < 4; ++n)
          acc[m][n] = __builtin_amdgcn_mfma_f32_16x16x32_bf16(af[m], bfr[n], acc[m][n], 0, 0, 0);
    }
    __syncthreads();
  }
  const int rr = (lane >> 4) * 4;
#pragma unroll
  for (int m = 0; m < 4; ++m)
#pragma unroll
    for (int n = 0; n < 4; ++n)
#pragma unroll
      for (int j = 0; j < 4; ++j) {
        int row = bm * 128 + wr + m * 16 + rr + j;
        int col = bn * 128 + wc + n * 16 + ar;
        if (OUT_BF16)
          ((short*)Cv)[(size_t)row * N + col] = f2bf(acc[m][n][j]);
        else
          ((float*)Cv)[(size_t)row * N + col] = acc[m][n][j];
      }
}

// ---------------- fused RMSNorm + RoPE, in-place on bf16, one wave per row -----
__global__ __launch_bounds__(256)
void normrope_kernel(short* __restrict__ X, const float* __restrict__ cosb,
                     const float* __restrict__ sinb, const float* __restrict__ w,
                     int headsPerS, int rowsPerS) {
  const int wid = threadIdx.x >> 6, lane = threadIdx.x & 63;
  const int r = blockIdx.x * 4 + wid;
  const int s = r / headsPerS, h = r % headsPerS;
  const size_t base = (size_t)(s * rowsPerS + h) * 128;
  float x1 = bf2f(X[base + lane]);
  float x2 = bf2f(X[base + 64 + lane]);
  float ss = x1 * x1 + x2 * x2;
#pragma unroll
  for (int m = 1; m < 64; m <<= 1) ss += __shfl_xor(ss, m);
  float inv = rsqrtf(ss * (1.0f / 128.0f) + 1e-6f);
  float n1 = x1 * inv * (1.0f + w[lane]);
  float n2 = x2 * inv * (1.0f + w[lane + 64]);
  float c1 = cosb[s * 128 + lane], sn1 = sinb[s * 128 + lane];
  float c2 = cosb[s * 128 + 64 + lane], sn2 = sinb[s * 128 + 64 + lane];
  X[base + lane] = f2bf(n1 * c1 - n2 * sn1);
  X[base + 64 + lane] = f2bf(n2 * c2 + n1 * sn2);
}

// ---------------- flash attention: causal, GQA 4:1, softcap, fixed-max softmax -
// softcap bounds s to [-50,50] => fixed max 0 is safe: p=e^s in [e^-50, e^50].
// grid: (qb reversed for LPT, h). KV combined buffer: row stride 2048 shorts,
// K at col 0, V at col 1024.
__global__ __launch_bounds__(256)
void attn_kernel(const short* __restrict__ Q, const short* __restrict__ KV,
                 short* __restrict__ O) {
  __shared__ short Ks[64][136];
  __shared__ short Vt[128][72];
  __shared__ short Ps[4][16][72];
  const int tid = threadIdx.x;
  const int qb = 31 - blockIdx.x;          // LPT: longest blocks dispatch first
  const int h = blockIdx.y;
  const int hk = h >> 2;
  const int wid = tid >> 6, lane = tid & 63;
  const int ar = lane & 15, g = lane >> 4, ko = g * 8;
  const int rbase = g * 4;
  const int q0 = qb * 64 + wid * 16;

  s16x8 qf[4];
#pragma unroll
  for (int ks = 0; ks < 4; ++ks)
    qf[ks] = *(const s16x8*)&Q[(size_t)(q0 + ar) * 4096 + h * 128 + ks * 32 + ko];

  const f32x4 fz = {0.f, 0.f, 0.f, 0.f};
  float l_l[4] = {0.f, 0.f, 0.f, 0.f};     // per-lane partial row sums
  f32x4 oacc[8];
#pragma unroll
  for (int n = 0; n < 8; ++n) oacc[n] = fz;

  for (int kb = 0; kb <= qb; ++kb) {
    // stage K tile 64x128 (linear b128 copy)
#pragma unroll
    for (int i = 0; i < 4; ++i) {
      int idx = tid + i * 256;
      int row = idx >> 4, c8 = (idx & 15) * 8;
      *(s16x8*)&Ks[row][c8] =
          *(const s16x8*)&KV[(size_t)(kb * 64 + row) * 2048 + hk * 128 + c8];
    }
    // stage V transposed
#pragma unroll
    for (int i = 0; i < 8; ++i) {
      int idx = tid + i * 256;
      int d = idx & 127, kk4 = (idx >> 7) * 4;
      const short* vp = &KV[(size_t)(kb * 64 + kk4) * 2048 + 1024 + hk * 128 + d];
      s16x4 tv;
      tv[0] = vp[0]; tv[1] = vp[2048]; tv[2] = vp[4096]; tv[3] = vp[6144];
      *(s16x4*)&Vt[d][kk4] = tv;
    }
    __syncthreads();

    // S = Q K^T
    f32x4 sacc[4];
#pragma unroll
    for (int n = 0; n < 4; ++n) sacc[n] = fz;
#pragma unroll
    for (int ks = 0; ks < 4; ++ks)
#pragma unroll
      for (int n = 0; n < 4; ++n) {
        s16x8 bfr = *(const s16x8*)&Ks[n * 16 + ar][ks * 32 + ko];
        sacc[n] = __builtin_amdgcn_mfma_f32_16x16x32_bf16(qf[ks], bfr, sacc[n], 0, 0, 0);
      }

    // softcap (exp-form tanh) + exp, fixed max; mask only on diagonal tile
    const bool last = (kb == qb);
#pragma unroll
    for (int n = 0; n < 4; ++n)
#pragma unroll
      for (int j = 0; j < 4; ++j) {
        float t = __expf(sacc[n][j] * TANH_K);
        float sc = 50.f - 100.f / (t + 1.f);   // = 50*tanh(s*SCALING/50)
        float p = __expf(sc);
        if (last) {
          int kkg = kb * 64 + n * 16 + ar;
          if (kkg > q0 + rbase + j) p = 0.f;
        }
        l_l[j] += p;
        Ps[wid][rbase + j][n * 16 + ar] = f2bf(p);
      }

    // O += P V
#pragma unroll
    for (int ks = 0; ks < 2; ++ks) {
      s16x8 pa = *(const s16x8*)&Ps[wid][ar][ks * 32 + ko];
#pragma unroll
      for (int n = 0; n < 8; ++n) {
        s16x8 bfr = *(const s16x8*)&Vt[n * 16 + ar][ks * 32 + ko];
        oacc[n] = __builtin_amdgcn_mfma_f32_16x16x32_bf16(pa, bfr, oacc[n], 0, 0, 0);
      }
    }
    __syncthreads();
  }

  // reduce l across the 16-lane row groups (deferred from the k-loop)
#pragma unroll
  for (int j = 0; j < 4; ++j) {
#pragma unroll
    for (int mm = 1; mm < 16; mm <<= 1) l_l[j] += __shfl_xor(l_l[j], mm);
  }
  float rl[4];
#pragma unroll
  for (int j = 0; j < 4; ++j) rl[j] = 1.0f / l_l[j];
#pragma unroll
  for (int n = 0; n < 8; ++n)
#pragma unroll
    for (int j = 0; j < 4; ++j) {
      int q = q0 + rbase + j;
      int d = n * 16 + ar;
      O[(size_t)q * 4096 + h * 128 + d] = f2bf(oacc[n][j] * rl[j]);
    }
}

extern "C" void kernel_launch(void* const* d_in, const int* in_sizes, int n_in,
                              void* d_out, int out_size, void* d_ws, size_t ws_size,
                              hipStream_t stream) {
  const float* hs   = (const float*)d_in[0];
  const float* cosb = (const float*)d_in[1];
  const float* sinb = (const float*)d_in[2];
  // d_in[3]: causal mask, applied analytically
  const float* Wq = (const float*)d_in[4];
  const float* Wk = (const float*)d_in[5];
  const float* Wv = (const float*)d_in[6];
  const float* Wo = (const float*)d_in[7];
  const float* qw = (const float*)d_in[8];
  const float* kw = (const float*)d_in[9];
  float* out = (float*)d_out;

  // ws layout (67.1 MB total, same footprint as round-0):
  char* ws = (char*)d_ws;
  short* hsb = (short*)ws;                    // [0, 10.49M)   2048x2560 bf16
  short* WkT = (short*)(ws + 10485760);       // [10.49, 15.73M) 1024x2560
  short* WvT = (short*)(ws + 15728640);       // [15.73, 20.97M) 1024x2560 (contig with WkT => 2048x2560)
  short* WqT = (short*)(ws + 20971520);       // [20.97, 41.94M) 4096x2560
  short* Qb  = (short*)(ws + 41943040);       // [41.94, 58.72M) 2048x4096
  short* KVb = (short*)(ws + 58720256);       // [58.72, 67.11M) 2048x2048 (K | V)
  short* ao  = (short*)ws;                    // alias hsb+WkT+WvT (dead after GEMMs)
  short* WoT = (short*)(ws + 20971520);       // alias WqT (dead after Q-GEMM)

  dim3 blk(256), cblk(64, 4);
  // weight/activation conversion (memory-bound, ~30us total)
  convT_kernel<<<dim3(40, 16), cblk, 0, stream>>>(Wk, WkT, 2560, 1024);
  convT_kernel<<<dim3(40, 16), cblk, 0, stream>>>(Wv, WvT, 2560, 1024);
  convT_kernel<<<dim3(40, 64), cblk, 0, stream>>>(Wq, WqT, 2560, 4096);
  conv16_kernel<<<5120, blk, 0, stream>>>(hs, hsb, 1310720);
  // projections (bf16 x bf16^T, m97-style)
  gemm_bb<1><<<dim3(32, 16), blk, 0, stream>>>(hsb, WqT, Qb, 4096, 2560);
  gemm_bb<1><<<dim3(16, 16), blk, 0, stream>>>(hsb, WkT, KVb, 2048, 2560);  // K|V fused
  // norm + rope (in-place)
  normrope_kernel<<<16384, blk, 0, stream>>>(Qb, cosb, sinb, qw, 32, 32);
  normrope_kernel<<<4096,  blk, 0, stream>>>(KVb, cosb, sinb, kw, 8, 16);
  // Wo transpose into dead WqT region, then attention into dead hsb region
  convT_kernel<<<dim3(64, 40), cblk, 0, stream>>>(Wo, WoT, 4096, 2560);
  attn_kernel<<<dim3(32, 32), blk, 0, stream>>>(Qb, KVb, ao);
  // output projection
  gemm_bb<0><<<dim3(20, 16), blk, 0, stream>>>(ao, WoT, out, 2560, 4096);
}

// Round 5
// 393.964 us; speedup vs baseline: 1.7069x; 1.5450x over previous
//
#include <hip/hip_runtime.h>
#include <hip/hip_bf16.h>

typedef __attribute__((ext_vector_type(4))) float f32x4;
typedef __attribute__((ext_vector_type(4))) float fl4;
typedef __attribute__((ext_vector_type(8))) short s16x8;
typedef __attribute__((ext_vector_type(4))) short s16x4;

#define SCALING_C 0.1889822365046136f
// 2*SCALING/50
#define TANH_K 0.007559289460184544f

__device__ __forceinline__ short f2bf(float f) {
  union { float f; unsigned u; } v; v.f = f;
  unsigned r = v.u + 0x7fffu + ((v.u >> 16) & 1u);
  return (short)(r >> 16);
}
__device__ __forceinline__ float bf2f(short s) {
  union { unsigned u; float f; } v; v.u = ((unsigned)(unsigned short)s) << 16;
  return v.f;
}

#define GLOAD_LDS16(g, l)                                                          \
  __builtin_amdgcn_global_load_lds(                                                \
      (const __attribute__((address_space(1))) void*)(g),                          \
      (__attribute__((address_space(3))) void*)(l), 16, 0, 0)

// ---------------- transpose + fp32->bf16 convert: WT[n][k] = bf16(W[k][n]) -----
__global__ __launch_bounds__(256)
void convT_kernel(const float* __restrict__ W, short* __restrict__ WT, int K, int N) {
  __shared__ float T[64][65];
  const int tx = threadIdx.x, ty = threadIdx.y;   // (64,4)
  const int k0 = blockIdx.x * 64, n0 = blockIdx.y * 64;
#pragma unroll
  for (int i = 0; i < 16; ++i) {
    int r = ty + i * 4;
    T[r][tx] = W[(size_t)(k0 + r) * N + n0 + tx];
  }
  __syncthreads();
#pragma unroll
  for (int i = 0; i < 16; ++i) {
    int r = ty + i * 4;
    WT[(size_t)(n0 + r) * K + k0 + tx] = f2bf(T[tx][r]);
  }
}

// ---------------- fp32 -> bf16 elementwise (hidden states) ----------------
__global__ __launch_bounds__(256)
void conv16_kernel(const float* __restrict__ X, short* __restrict__ Y, int n4) {
  int i = blockIdx.x * 256 + threadIdx.x;
  if (i < n4) {
    fl4 v = *(const fl4*)&X[(size_t)i * 4];
    s16x4 o;
    o[0] = f2bf(v[0]); o[1] = f2bf(v[1]); o[2] = f2bf(v[2]); o[3] = f2bf(v[3]);
    *(s16x4*)&Y[(size_t)i * 4] = o;
  }
}

// ---------------- GEMM: C = A @ Bt^T ; A MxK bf16 rows, Bt NxK bf16 rows -------
template<int OUT_BF16>
__global__ __launch_bounds__(256)
void gemm_bb(const short* __restrict__ A, const short* __restrict__ Bt,
             void* __restrict__ Cv, int N, int K) {
  __shared__ short As[8192];   // 128 rows x 64 shorts
  __shared__ short Bs[8192];
  const int tid = threadIdx.x;
  const int bm = blockIdx.y, bn = blockIdx.x;
  const int wid = tid >> 6, lane = tid & 63;
  const int wr = (wid >> 1) * 64, wc = (wid & 1) * 64;
  const int ar = lane & 15, g = lane >> 4;

  const f32x4 fz = {0.f, 0.f, 0.f, 0.f};
  f32x4 acc[4][4];
#pragma unroll
  for (int m = 0; m < 4; ++m)
#pragma unroll
    for (int n = 0; n < 4; ++n) acc[m][n] = fz;

  const short* Abase = A + (size_t)(bm * 128) * K;
  const short* Bbase = Bt + (size_t)(bn * 128) * K;
  const int u0 = wid * 256 + lane;

  for (int k0 = 0; k0 < K; k0 += 64) {
#pragma unroll
    for (int i = 0; i < 4; ++i) {
      int u = u0 + i * 64;
      int r = u >> 3;
      int cs = (u & 7) ^ (r & 7);
      size_t goff = (size_t)r * K + k0 + cs * 8;
      GLOAD_LDS16(Abase + goff, &As[(wid * 256 + i * 64) * 8]);
      GLOAD_LDS16(Bbase + goff, &Bs[(wid * 256 + i * 64) * 8]);
    }
    __syncthreads();
#pragma unroll
    for (int ks = 0; ks < 2; ++ks) {
      s16x8 af[4], bfr[4];
#pragma unroll
      for (int m = 0; m < 4; ++m) {
        int r = wr + m * 16 + ar;
        af[m] = *(const s16x8*)&As[r * 64 + (((ks * 4 + g) ^ (r & 7)) * 8)];
      }
#pragma unroll
      for (int n = 0; n < 4; ++n) {
        int r = wc + n * 16 + ar;
        bfr[n] = *(const s16x8*)&Bs[r * 64 + (((ks * 4 + g) ^ (r & 7)) * 8)];
      }
#pragma unroll
      for (int m = 0; m < 4; ++m)
#pragma unroll
        for (int n = 0; n < 4; ++n)
          acc[m][n] = __builtin_amdgcn_mfma_f32_16x16x32_bf16(af[m], bfr[n], acc[m][n], 0, 0, 0);
    }
    __syncthreads();
  }
  const int rr = (lane >> 4) * 4;
#pragma unroll
  for (int m = 0; m < 4; ++m)
#pragma unroll
    for (int n = 0; n < 4; ++n)
#pragma unroll
      for (int j = 0; j < 4; ++j) {
        int row = bm * 128 + wr + m * 16 + rr + j;
        int col = bn * 128 + wc + n * 16 + ar;
        if (OUT_BF16)
          ((short*)Cv)[(size_t)row * N + col] = f2bf(acc[m][n][j]);
        else
          ((float*)Cv)[(size_t)row * N + col] = acc[m][n][j];
      }
}

// ---------------- fused RMSNorm + RoPE, in-place on bf16, one wave per row -----
__global__ __launch_bounds__(256)
void normrope_kernel(short* __restrict__ X, const float* __restrict__ cosb,
                     const float* __restrict__ sinb, const float* __restrict__ w,
                     int headsPerS, int rowsPerS) {
  const int wid = threadIdx.x >> 6, lane = threadIdx.x & 63;
  const int r = blockIdx.x * 4 + wid;
  const int s = r / headsPerS, h = r % headsPerS;
  const size_t base = (size_t)(s * rowsPerS + h) * 128;
  float x1 = bf2f(X[base + lane]);
  float x2 = bf2f(X[base + 64 + lane]);
  float ss = x1 * x1 + x2 * x2;
#pragma unroll
  for (int m = 1; m < 64; m <<= 1) ss += __shfl_xor(ss, m);
  float inv = rsqrtf(ss * (1.0f / 128.0f) + 1e-6f);
  float n1 = x1 * inv * (1.0f + w[lane]);
  float n2 = x2 * inv * (1.0f + w[lane + 64]);
  float c1 = cosb[s * 128 + lane], sn1 = sinb[s * 128 + lane];
  float c2 = cosb[s * 128 + 64 + lane], sn2 = sinb[s * 128 + 64 + lane];
  X[base + lane] = f2bf(n1 * c1 - n2 * sn1);
  X[base + 64 + lane] = f2bf(n2 * c2 + n1 * sn2);
}

// ---------------- flash attention v2: pipelined, mirrored-pair balanced --------
// Block (bx,h): processes q-chunk bx (tiles 0..bx) then chunk 31-bx (tiles
// 0..31-bx): exactly 33 kv-tiles per block. Grid (16,32)=512 blocks = 2/CU.
// Double-buffered K (global_load_lds, XOR-swz source) and Vt (b128 reg-staged,
// transposed b32 LDS writes); one barrier per tile; vmcnt drained after compute.
// Fixed-max softmax (softcap bounds s to [-50,50] so exp(s) is safe).
__global__ __launch_bounds__(256)
void attn_kernel(const short* __restrict__ Q, const short* __restrict__ K,
                 const short* __restrict__ V, short* __restrict__ O) {
  __shared__ short Ks[2][8192];   // [kv 64][d 128] chunk-XOR swizzled
  __shared__ short Vt[2][8192];   // [d 128][kv 64] chunk-XOR swizzled
  __shared__ short Ps[4][16][72];
  const int tid = threadIdx.x;
  const int h = blockIdx.y, hk = h >> 2;
  const int wid = tid >> 6, lane = tid & 63;
  const int ar = lane & 15, g = lane >> 4, ko = g * 8;
  const int rbase = g * 4;
  const int qA = blockIdx.x, qB = 31 - blockIdx.x;

  const short* Kb = K + hk * 128;
  const short* Vb = V + hk * 128;
  const int vkv = (tid & 31) * 2;   // kv pair
  const int vdb = tid >> 5;         // d block (16 d's)

  const f32x4 fz = {0.f, 0.f, 0.f, 0.f};
  s16x8 qf[4], vld[4];
  f32x4 oacc[8];
  float l_l[4];

  int qcur = qA;
  int q0 = qA * 64 + wid * 16;
#pragma unroll
  for (int ks = 0; ks < 4; ++ks)
    qf[ks] = *(const s16x8*)&Q[(size_t)(q0 + ar) * 4096 + h * 128 + ks * 32 + ko];
#pragma unroll
  for (int n = 0; n < 8; ++n) oacc[n] = fz;
#pragma unroll
  for (int j = 0; j < 4; ++j) l_l[j] = 0.f;

  auto issueK = [&](int b, int kb) {
    const short* src = Kb + (size_t)kb * 64 * 1024;
#pragma unroll
    for (int i = 0; i < 4; ++i) {
      int u = wid * 64 + i * 256 + lane;
      int r = u >> 4, c = u & 15;
      int cs = c ^ (r & 7);
      GLOAD_LDS16(src + r * 1024 + cs * 8, &Ks[b][(wid * 64 + i * 256) * 8]);
    }
  };
  auto issueV = [&](int kb) {
    const short* src = Vb + (size_t)(kb * 64 + vkv) * 1024 + vdb * 16;
    vld[0] = *(const s16x8*)(src);
    vld[1] = *(const s16x8*)(src + 8);
    vld[2] = *(const s16x8*)(src + 1024);
    vld[3] = *(const s16x8*)(src + 1032);
  };
  auto writeVt = [&](int b) {
#pragma unroll
    for (int half = 0; half < 2; ++half)
#pragma unroll
      for (int j = 0; j < 8; ++j) {
        int d = vdb * 16 + half * 8 + j;     // d&7 == j
        int addr = d * 64 + (((vkv >> 3) ^ j) * 8) + (vkv & 7);
        unsigned lo = (unsigned short)vld[half][j];
        unsigned hi = (unsigned short)vld[2 + half][j];
        *(unsigned*)&Vt[b][addr] = lo | (hi << 16);
      }
  };

  // prologue: stage tile 0
  issueK(0, 0);
  issueV(0);
  asm volatile("s_waitcnt vmcnt(0)" ::: "memory");
  writeVt(0);
  __syncthreads();

  int buf = 0;
  for (int step = 0; step < 33; ++step) {
    const int kb = (step <= qA) ? step : step - qA - 1;
    if (step < 32) {
      const int nkb = (step + 1 <= qA) ? step + 1 : step - qA;
      issueK(buf ^ 1, nkb);
      issueV(nkb);
    }

    // ---- compute tile (qcur, kb) from buf ----
    f32x4 sacc[4];
#pragma unroll
    for (int n = 0; n < 4; ++n) sacc[n] = fz;
#pragma unroll
    for (int ks = 0; ks < 4; ++ks)
#pragma unroll
      for (int n = 0; n < 4; ++n) {
        int r = n * 16 + ar;
        s16x8 bfr = *(const s16x8*)&Ks[buf][r * 128 + (((ks * 4 + g) ^ (r & 7)) * 8)];
        sacc[n] = __builtin_amdgcn_mfma_f32_16x16x32_bf16(qf[ks], bfr, sacc[n], 0, 0, 0);
      }

    const bool last = (kb == qcur);
#pragma unroll
    for (int n = 0; n < 4; ++n)
#pragma unroll
      for (int j = 0; j < 4; ++j) {
        float t = __expf(sacc[n][j] * TANH_K);
        float sc = 50.f - 100.f / (t + 1.f);   // 50*tanh(s*SCALING/50)
        float p = __expf(sc);
        if (last) {
          int kkg = kb * 64 + n * 16 + ar;
          if (kkg > q0 + rbase + j) p = 0.f;
        }
        l_l[j] += p;
        Ps[wid][rbase + j][n * 16 + ar] = f2bf(p);
      }

#pragma unroll
    for (int ks = 0; ks < 2; ++ks) {
      s16x8 pa = *(const s16x8*)&Ps[wid][ar][ks * 32 + ko];
#pragma unroll
      for (int n = 0; n < 8; ++n) {
        int d = n * 16 + ar;
        s16x8 bfr = *(const s16x8*)&Vt[buf][d * 64 + (((ks * 4 + g) ^ (d & 7)) * 8)];
        oacc[n] = __builtin_amdgcn_mfma_f32_16x16x32_bf16(pa, bfr, oacc[n], 0, 0, 0);
      }
    }

    // ---- drain prefetch, publish next Vt, flip ----
    if (step < 32) {
      asm volatile("s_waitcnt vmcnt(0)" ::: "memory");
      writeVt(buf ^ 1);
    }
    __syncthreads();
    buf ^= 1;

    if (step == qA) {
      // epilogue for chunk A
      float rl[4];
#pragma unroll
      for (int j = 0; j < 4; ++j) {
#pragma unroll
        for (int mm = 1; mm < 16; mm <<= 1) l_l[j] += __shfl_xor(l_l[j], mm);
        rl[j] = 1.0f / l_l[j];
      }
#pragma unroll
      for (int n = 0; n < 8; ++n)
#pragma unroll
        for (int j = 0; j < 4; ++j)
          O[(size_t)(q0 + rbase + j) * 4096 + h * 128 + n * 16 + ar] =
              f2bf(oacc[n][j] * rl[j]);
      // switch to chunk B
      qcur = qB;
      q0 = qB * 64 + wid * 16;
#pragma unroll
      for (int ks = 0; ks < 4; ++ks)
        qf[ks] = *(const s16x8*)&Q[(size_t)(q0 + ar) * 4096 + h * 128 + ks * 32 + ko];
#pragma unroll
      for (int n = 0; n < 8; ++n) oacc[n] = fz;
#pragma unroll
      for (int j = 0; j < 4; ++j) l_l[j] = 0.f;
    }
  }

  // epilogue for chunk B
  float rl[4];
#pragma unroll
  for (int j = 0; j < 4; ++j) {
#pragma unroll
    for (int mm = 1; mm < 16; mm <<= 1) l_l[j] += __shfl_xor(l_l[j], mm);
    rl[j] = 1.0f / l_l[j];
  }
#pragma unroll
  for (int n = 0; n < 8; ++n)
#pragma unroll
    for (int j = 0; j < 4; ++j)
      O[(size_t)(q0 + rbase + j) * 4096 + h * 128 + n * 16 + ar] =
          f2bf(oacc[n][j] * rl[j]);
}

extern "C" void kernel_launch(void* const* d_in, const int* in_sizes, int n_in,
                              void* d_out, int out_size, void* d_ws, size_t ws_size,
                              hipStream_t stream) {
  const float* hs   = (const float*)d_in[0];
  const float* cosb = (const float*)d_in[1];
  const float* sinb = (const float*)d_in[2];
  // d_in[3]: causal mask, applied analytically
  const float* Wq = (const float*)d_in[4];
  const float* Wk = (const float*)d_in[5];
  const float* Wv = (const float*)d_in[6];
  const float* Wo = (const float*)d_in[7];
  const float* qw = (const float*)d_in[8];
  const float* kw = (const float*)d_in[9];
  float* out = (float*)d_out;

  char* ws = (char*)d_ws;
  short* hsb = (short*)ws;                    // [0, 10.49M)
  short* WkT = (short*)(ws + 10485760);       // [10.49, 15.73M)
  short* WvT = (short*)(ws + 15728640);       // [15.73, 20.97M)
  short* WqT = (short*)(ws + 20971520);       // [20.97, 41.94M)
  short* Qb  = (short*)(ws + 41943040);       // [41.94, 58.72M)
  short* Kbf = (short*)(ws + 58720256);       // [58.72, 62.91M)
  short* Vbf = (short*)(ws + 62914560);       // [62.91, 67.11M)
  short* ao  = (short*)ws;                    // alias hsb+WkT+WvT (dead)
  short* WoT = (short*)(ws + 20971520);       // alias WqT (dead after Q-GEMM)

  dim3 blk(256), cblk(64, 4);
  convT_kernel<<<dim3(40, 16), cblk, 0, stream>>>(Wk, WkT, 2560, 1024);
  convT_kernel<<<dim3(40, 16), cblk, 0, stream>>>(Wv, WvT, 2560, 1024);
  convT_kernel<<<dim3(40, 64), cblk, 0, stream>>>(Wq, WqT, 2560, 4096);
  conv16_kernel<<<5120, blk, 0, stream>>>(hs, hsb, 1310720);
  gemm_bb<1><<<dim3(32, 16), blk, 0, stream>>>(hsb, WqT, Qb, 4096, 2560);
  gemm_bb<1><<<dim3(8, 16),  blk, 0, stream>>>(hsb, WkT, Kbf, 1024, 2560);
  gemm_bb<1><<<dim3(8, 16),  blk, 0, stream>>>(hsb, WvT, Vbf, 1024, 2560);
  normrope_kernel<<<16384, blk, 0, stream>>>(Qb, cosb, sinb, qw, 32, 32);
  normrope_kernel<<<4096,  blk, 0, stream>>>(Kbf, cosb, sinb, kw, 8, 8);
  convT_kernel<<<dim3(64, 40), cblk, 0, stream>>>(Wo, WoT, 4096, 2560);
  attn_kernel<<<dim3(16, 32), blk, 0, stream>>>(Qb, Kbf, Vbf, ao);
  gemm_bb<0><<<dim3(20, 16), blk, 0, stream>>>(ao, WoT, out, 2560, 4096);
}